// Round 8
// baseline (272.719 us; speedup 1.0000x reference)
//
#include <hip/hip_runtime.h>
#include <math.h>

// Problem constants (B=8, S=512, T=4, D=128)
constexpr int M     = 16384;     // keys = B*S*T
constexpr int NANCH = 12288;     // anchors = B*S*(T-1)
constexpr int ELEM  = 2097152;   // B*S*T*D

typedef __bf16 bf16x8 __attribute__((ext_vector_type(8)));
typedef float f32x4 __attribute__((ext_vector_type(4)));
typedef unsigned int uint;

// Ksw: 16B slots, slot(row r, chunk c) = (r>>4)*256 + c*16 + (r&15)
//   -> k_sim B-fragment ds_read_b128 = base + lane*16 (conflict-free), staging identity.
// Asw: ROW-major 16B slots, slot(row a, chunk c) = a*16 + c
//   -> k_prep writes fully coalesced; k_sim reads af per-lane from global (L2-hot, one-time).

__device__ inline float waveRedSum(float v) {
#pragma unroll
  for (int off = 32; off > 0; off >>= 1) v += __shfl_down(v, off, 64);
  return v;
}

__device__ inline unsigned short f2bf(float x) {  // RNE
  unsigned int u = __float_as_uint(x);
  u += 0x7FFF + ((u >> 16) & 1);
  return (unsigned short)(u >> 16);
}
__device__ inline uint packbf(float x, float y) {
  return ((uint)f2bf(y) << 16) | (uint)f2bf(x);
}

__device__ inline float fast_exp2(float x) {  // v_exp_f32: 2^x
  float r;
  asm("v_exp_f32 %0, %1" : "=v"(r) : "v"(x));
  return r;
}

__device__ inline void load_lds16(uint4* lds, const uint4* g) {
  __builtin_amdgcn_global_load_lds(
      (const __attribute__((address_space(1))) unsigned int*)g,
      (__attribute__((address_space(3))) unsigned int*)lds, 16, 0, 0);
}

// ---------------- K1: fused prep (1024 blocks x 16 rows) ----------------
__global__ __launch_bounds__(256) void k_prep(
    const float* __restrict__ H, const float* __restrict__ spikes,
    const float* __restrict__ mem, uint* __restrict__ Ksw, uint* __restrict__ Asw,
    float* __restrict__ MiL, float* __restrict__ Pspike, float* __restrict__ Pmem) {
  __shared__ float ps[512];
  __shared__ float scb[16];
  __shared__ uint tb[1024];     // 16 rows x 64 uints in Ksw slot order
  __shared__ float buf2[2][4];
  const int g = blockIdx.x, t = threadIdx.x;

  const float4* H4 = (const float4*)H + (size_t)g * 512;
  float4 fa = H4[t];
  float4 fb = H4[t + 256];
  ps[t]       = fa.x * fa.x + fa.y * fa.y + fa.z * fa.z + fa.w * fa.w;
  ps[t + 256] = fb.x * fb.x + fb.y * fb.y + fb.z * fb.z + fb.w * fb.w;
  __syncthreads();
  if (t < 16) {
    float ss = 0.f;
#pragma unroll
    for (int j = 0; j < 32; ++j) ss += ps[t * 32 + ((j + t) & 31)];  // rotated, conflict-free
    float sc = 10.0f / fmaxf(sqrtf(ss), 1e-12f);
    scb[t] = sc;
    if ((t & 3) != 3)
      MiL[g * 12 + (t >> 2) * 3 + (t & 3)] = 144.269504088896f / sc;  // (100/sc)*log2e
  }
  __syncthreads();

  const int ja = t & 31;                    // float4 index within row
  const int rla = t >> 5, rlb = 8 + (t >> 5);
  {
    float sa = scb[rla];
    uint2 ka = {packbf(fa.x * sa, fa.y * sa), packbf(fa.z * sa, fa.w * sa)};
    *(uint2*)&tb[((ja >> 1) * 16 + rla) * 4 + (ja & 1) * 2] = ka;
    float sb = scb[rlb];
    uint2 kb = {packbf(fb.x * sb, fb.y * sb), packbf(fb.z * sb, fb.w * sb)};
    *(uint2*)&tb[((ja >> 1) * 16 + rlb) * 4 + (ja & 1) * 2] = kb;
    if ((rla & 3) != 3) {  // anchor row -> row-major Asw, fully coalesced
      size_t i = (size_t)g * 12 + (rla >> 2) * 3 + (rla & 3);
      uint2 aa = {packbf(fa.x, fa.y), packbf(fa.z, fa.w)};
      *(uint2*)&Asw[i * 64 + ja * 2] = aa;
    }
    if ((rlb & 3) != 3) {
      size_t i = (size_t)g * 12 + (rlb >> 2) * 3 + (rlb & 3);
      uint2 aa = {packbf(fb.x, fb.y), packbf(fb.z, fb.w)};
      *(uint2*)&Asw[i * 64 + ja * 2] = aa;
    }
  }
  __syncthreads();
  ((uint4*)Ksw)[(size_t)g * 256 + t] = ((const uint4*)tb)[t];  // coalesced 4 KB

  // spikes mean + mem^2 partials (512 float4 each per block)
  const float4* s4 = (const float4*)spikes + (size_t)g * 512;
  const float4* m4 = (const float4*)mem + (size_t)g * 512;
  float4 s0 = s4[t], s1 = s4[t + 256];
  float4 m0 = m4[t], m1 = m4[t + 256];
  float ssp = s0.x + s0.y + s0.z + s0.w + s1.x + s1.y + s1.z + s1.w;
  float smm = m0.x * m0.x + m0.y * m0.y + m0.z * m0.z + m0.w * m0.w +
              m1.x * m1.x + m1.y * m1.y + m1.z * m1.z + m1.w * m1.w;
  ssp = waveRedSum(ssp);
  smm = waveRedSum(smm);
  int w = t >> 6, lane = t & 63;
  if (lane == 0) { buf2[0][w] = ssp; buf2[1][w] = smm; }
  __syncthreads();
  if (t == 0) {
    Pspike[g] = buf2[0][0] + buf2[0][1] + buf2[0][2] + buf2[0][3];
    Pmem[g]   = buf2[1][0] + buf2[1][1] + buf2[1][2] + buf2[1][3];
  }
}

// ---------------- K2: MFMA sim-GEMM + fused exp + diag extract ----------------
// 128 anchors x 1024 keys per block; af per-lane from global Asw; single 32 KB
// K-tile buffer, 2 barriers/tile; 4 blocks/CU for inter-block overlap.
constexpr int KSPLIT = 16;
constexpr int KEYS_PB = M / KSPLIT;   // 1024
constexpr int NT = KEYS_PB / 128;     // 8

__global__ __launch_bounds__(256, 4) void k_sim(
    const uint4* __restrict__ Ksw, const uint* __restrict__ Asw,
    const float* __restrict__ MiL, float* __restrict__ sumexp,
    float* __restrict__ simii) {
  __shared__ uint4 Tile[2048];  // 32 KB, one 128-key tile
  const int tid = threadIdx.x;
  const int lane = tid & 63, w = tid >> 6;
  const int wm = w & 1, wn = w >> 1;
  const int wmo = wm * 64;
  const int a0 = blockIdx.y * 128;
  const int k0 = blockIdx.x * KEYS_PB;
  const int lcol = lane & 15, lhi = lane >> 4;
  const bool dblk = ((int)blockIdx.x == (int)(blockIdx.y >> 3));
  const int diagT2 = (a0 - k0) >> 7;  // valid only when dblk

  // A fragments: per-lane contiguous loads from row-major Asw (one-time, L2-hot)
  bf16x8 af[4][4];
#pragma unroll
  for (int mi = 0; mi < 4; ++mi) {
    size_t a = (size_t)a0 + wmo + mi * 16 + lcol;
    const uint* base = Asw + a * 64;
#pragma unroll
    for (int ks = 0; ks < 4; ++ks)
      af[mi][ks] = *(const bf16x8*)(base + (ks * 4 + lhi) * 4);
  }
  float nmiL[4][4];
#pragma unroll
  for (int mi = 0; mi < 4; ++mi)
#pragma unroll
    for (int r = 0; r < 4; ++r)
      nmiL[mi][r] = -MiL[a0 + wmo + mi * 16 + lhi * 4 + r];

  float rs[4][4] = {};
  for (int t2 = 0; t2 < NT; ++t2) {
    const uint4* src = Ksw + ((size_t)k0 + t2 * 128) * 16;
#pragma unroll
    for (int it = 0; it < 8; ++it)
      load_lds16(Tile + it * 256 + tid, src + it * 256 + tid);
    __syncthreads();  // vmcnt drained: tile ready

    f32x4 acc[4][4] = {};
#pragma unroll
    for (int ks = 0; ks < 4; ++ks) {
      bf16x8 bfr[4];
#pragma unroll
      for (int nj = 0; nj < 4; ++nj)
        bfr[nj] = *(const bf16x8*)(Tile + (wn * 4 + nj) * 256 + ks * 64 + lane);
#pragma unroll
      for (int mi = 0; mi < 4; ++mi)
#pragma unroll
        for (int nj = 0; nj < 4; ++nj)
          acc[mi][nj] = __builtin_amdgcn_mfma_f32_16x16x32_bf16(af[mi][ks], bfr[nj], acc[mi][nj], 0, 0, 0);
    }

    // diagonal extraction: key column (global) == anchor index (one block/tile per a-tile)
    if (dblk && t2 == diagT2 && wm == wn && (lcol >> 2) == lhi) {
      int rr = lcol & 3;
#pragma unroll
      for (int mi = 0; mi < 4; ++mi) {
        f32x4 q = acc[mi][mi];
        float v = rr == 0 ? q[0] : rr == 1 ? q[1] : rr == 2 ? q[2] : q[3];
        simii[a0 + wmo + mi * 16 + lcol] = v;
      }
    }

    // fused epilogue: rs += 2^(sim*log2e - Mi*log2e)
#pragma unroll
    for (int mi = 0; mi < 4; ++mi)
#pragma unroll
      for (int nj = 0; nj < 4; ++nj)
#pragma unroll
        for (int r = 0; r < 4; ++r)
          rs[mi][r] += fast_exp2(fmaf(acc[mi][nj][r], 1.44269504088896f, nmiL[mi][r]));
    __syncthreads();  // all reads done before next tile's staging
  }

  // reduce over 16 key-columns, one atomic per anchor per wave
#pragma unroll
  for (int mi = 0; mi < 4; ++mi)
#pragma unroll
    for (int r = 0; r < 4; ++r) {
      float v = rs[mi][r];
      v += __shfl_xor(v, 1, 64);
      v += __shfl_xor(v, 2, 64);
      v += __shfl_xor(v, 4, 64);
      v += __shfl_xor(v, 8, 64);
      if (lcol == 0) atomicAdd(&sumexp[a0 + wmo + mi * 16 + lhi * 4 + r], v);
    }
}

// ---------------- K3: elementwise ce + partials + last-block finalize ----------------
__global__ __launch_bounds__(256) void k_fin(
    const float* __restrict__ sumexp, const float* __restrict__ simii,
    const float* __restrict__ MiL, const int* __restrict__ targets,
    float* __restrict__ Pce, float* __restrict__ Pnv,
    const float* __restrict__ Pspike, const float* __restrict__ Pmem,
    uint* __restrict__ cnt, float* __restrict__ out) {
  int t = threadIdx.x, w = t >> 6, lane = t & 63;
  int i = blockIdx.x * 256 + t;
  float ce = 0.f, nv = 0.f;
  if (targets[i / 3] != 0) {
    // ce = Mi + ln(sumexp) - sim_ii ; Mi = MiL*ln2
    ce = 0.69314718055994531f * MiL[i] + __logf(sumexp[i]) - simii[i];
    nv = 1.f;
  }
  ce = waveRedSum(ce);
  nv = waveRedSum(nv);
  __shared__ float buf[2][4];
  __shared__ int isLast;
  if (lane == 0) { buf[0][w] = ce; buf[1][w] = nv; }
  __syncthreads();
  if (t == 0) {
    float pce = buf[0][0] + buf[0][1] + buf[0][2] + buf[0][3];
    float pnv = buf[1][0] + buf[1][1] + buf[1][2] + buf[1][3];
    __hip_atomic_store(&Pce[blockIdx.x], pce, __ATOMIC_RELAXED, __HIP_MEMORY_SCOPE_AGENT);
    __hip_atomic_store(&Pnv[blockIdx.x], pnv, __ATOMIC_RELAXED, __HIP_MEMORY_SCOPE_AGENT);
    __threadfence();
    uint prev = __hip_atomic_fetch_add(cnt, 1u, __ATOMIC_ACQ_REL, __HIP_MEMORY_SCOPE_AGENT);
    isLast = (prev == gridDim.x - 1);
  }
  __syncthreads();
  if (!isLast) return;

  float a = 0.f, b = 0.f, c = 0.f, e = 0.f;
#pragma unroll
  for (int j = 0; j < 4; ++j) {
    a += __hip_atomic_load(&Pspike[t + j * 256], __ATOMIC_RELAXED, __HIP_MEMORY_SCOPE_AGENT);
    b += __hip_atomic_load(&Pmem[t + j * 256], __ATOMIC_RELAXED, __HIP_MEMORY_SCOPE_AGENT);
  }
  if (t < 48) {
    c = __hip_atomic_load(&Pce[t], __ATOMIC_RELAXED, __HIP_MEMORY_SCOPE_AGENT);
    e = __hip_atomic_load(&Pnv[t], __ATOMIC_RELAXED, __HIP_MEMORY_SCOPE_AGENT);
  }
  a = waveRedSum(a); b = waveRedSum(b); c = waveRedSum(c); e = waveRedSum(e);
  __shared__ float fb2[4][4];
  if (lane == 0) { fb2[0][w] = a; fb2[1][w] = b; fb2[2][w] = c; fb2[3][w] = e; }
  __syncthreads();
  if (t == 0) {
    float ssp = fb2[0][0] + fb2[0][1] + fb2[0][2] + fb2[0][3];
    float smm = fb2[1][0] + fb2[1][1] + fb2[1][2] + fb2[1][3];
    float cet = fb2[2][0] + fb2[2][1] + fb2[2][2] + fb2[2][3];
    float nvt = fb2[3][0] + fb2[3][1] + fb2[3][2] + fb2[3][3];
    float spike_rate = ssp / (float)ELEM;
    float dr = spike_rate - 0.02f;
    float spike_reg = dr * dr;
    float mem_reg = smm / (float)ELEM;
    float tcl = cet / fmaxf(nvt, 1.0f);
    out[0] = tcl + 0.01f * spike_reg + 0.001f * mem_reg;
    out[1] = tcl;
    out[2] = spike_reg;
    out[3] = mem_reg;
    out[4] = spike_rate;
  }
}

extern "C" void kernel_launch(void* const* d_in, const int* in_sizes, int n_in,
                              void* d_out, int out_size, void* d_ws, size_t ws_size,
                              hipStream_t stream) {
  const float* H = (const float*)d_in[0];
  const int* targets = (const int*)d_in[1];
  const float* spikes = (const float*)d_in[2];
  const float* mem = (const float*)d_in[3];
  float* out = (float*)d_out;
  float* ws = (float*)d_ws;

  float* sumexp = ws;                      // [0, 12288)
  uint*  cnt    = (uint*)(ws + 12288);     // [12288]
  float* simii  = ws + 12292;              // +12288 -> 24580
  float* MiL    = ws + 24580;              // +12288 -> 36868
  float* Pspike = ws + 36868;              // +1024  -> 37892
  float* Pmem   = ws + 37892;              // +1024  -> 38916
  float* Pce    = ws + 38916;              // +48    -> 38964
  float* Pnv    = ws + 38964;              // +48    -> 39012
  uint*  Ksw    = (uint*)(ws + 39012);     // M*64 uints (16B aligned)
  uint*  Asw    = Ksw + (size_t)M * 64;    // NANCH*64 uints

  hipMemsetAsync(ws, 0, 12292 * sizeof(float), stream);  // sumexp + cnt
  k_prep<<<1024, 256, 0, stream>>>(H, spikes, mem, Ksw, Asw, MiL, Pspike, Pmem);
  dim3 g2(KSPLIT, NANCH / 128);
  k_sim<<<g2, 256, 0, stream>>>((const uint4*)Ksw, Asw, MiL, sumexp, simii);
  k_fin<<<NANCH / 256, 256, 0, stream>>>(sumexp, simii, MiL, targets, Pce, Pnv,
                                         Pspike, Pmem, cnt, out);
}

// Round 9
// 146.260 us; speedup vs baseline: 1.8646x; 1.8646x over previous
//
#include <hip/hip_runtime.h>
#include <math.h>

// Problem constants (B=8, S=512, T=4, D=128)
constexpr int M     = 16384;     // keys = B*S*T
constexpr int NANCH = 12288;     // anchors = B*S*(T-1)
constexpr int ELEM  = 2097152;   // B*S*T*D

typedef __bf16 bf16x8 __attribute__((ext_vector_type(8)));
typedef float f32x4 __attribute__((ext_vector_type(4)));
typedef unsigned int uint;

// Ksw/Asw: 16B slots, slot(row r, chunk c) = (r>>4)*256 + c*16 + (r&15)
// -> MFMA fragment ds_read_b128 = base + lane*16 (conflict-free), staging identity.

__device__ inline float waveRedSum(float v) {
#pragma unroll
  for (int off = 32; off > 0; off >>= 1) v += __shfl_down(v, off, 64);
  return v;
}

__device__ inline unsigned short f2bf(float x) {  // RNE
  unsigned int u = __float_as_uint(x);
  u += 0x7FFF + ((u >> 16) & 1);
  return (unsigned short)(u >> 16);
}
__device__ inline uint packbf(float x, float y) {
  return ((uint)f2bf(y) << 16) | (uint)f2bf(x);
}

__device__ inline float fast_exp2(float x) {  // v_exp_f32: 2^x
  float r;
  asm("v_exp_f32 %0, %1" : "=v"(r) : "v"(x));
  return r;
}

__device__ inline void load_lds16(uint4* lds, const uint4* g) {
  __builtin_amdgcn_global_load_lds(
      (const __attribute__((address_space(1))) unsigned int*)g,
      (__attribute__((address_space(3))) unsigned int*)lds, 16, 0, 0);
}

// ---------------- K1: prep (1024 blocks x 16 rows): H -> Ksw/Asw/MiL ----------------
__global__ __launch_bounds__(256) void k_prep(
    const float* __restrict__ H, uint* __restrict__ Ksw, uint* __restrict__ Asw,
    float* __restrict__ MiL) {
  __shared__ float ps[512];
  __shared__ float scb[16];
  __shared__ uint tb[1024];     // 16 rows x 64 uints in slot order
  const int g = blockIdx.x, t = threadIdx.x;

  const float4* H4 = (const float4*)H + (size_t)g * 512;
  float4 fa = H4[t];
  float4 fb = H4[t + 256];
  ps[t]       = fa.x * fa.x + fa.y * fa.y + fa.z * fa.z + fa.w * fa.w;
  ps[t + 256] = fb.x * fb.x + fb.y * fb.y + fb.z * fb.z + fb.w * fb.w;
  __syncthreads();
  if (t < 16) {
    float ss = 0.f;
#pragma unroll
    for (int j = 0; j < 32; ++j) ss += ps[t * 32 + ((j + t) & 31)];  // rotated, conflict-free
    float sc = 10.0f / fmaxf(sqrtf(ss), 1e-12f);
    scb[t] = sc;
    if ((t & 3) != 3)
      MiL[g * 12 + (t >> 2) * 3 + (t & 3)] = 144.269504088896f / sc;  // (100/sc)*log2e
  }
  __syncthreads();

  const int ja = t & 31;                    // float4 index within row
  const int rla = t >> 5, rlb = 8 + (t >> 5);
  {
    float sa = scb[rla];
    uint2 ka = {packbf(fa.x * sa, fa.y * sa), packbf(fa.z * sa, fa.w * sa)};
    *(uint2*)&tb[((ja >> 1) * 16 + rla) * 4 + (ja & 1) * 2] = ka;
    float sb = scb[rlb];
    uint2 kb = {packbf(fb.x * sb, fb.y * sb), packbf(fb.z * sb, fb.w * sb)};
    *(uint2*)&tb[((ja >> 1) * 16 + rlb) * 4 + (ja & 1) * 2] = kb;
    if ((rla & 3) != 3) {  // anchor row: raw bf16 scatter to Asw slot layout
      int i = g * 12 + (rla >> 2) * 3 + (rla & 3);
      uint2 aa = {packbf(fa.x, fa.y), packbf(fa.z, fa.w)};
      *(uint2*)&Asw[((size_t)(i >> 4) * 256 + (ja >> 1) * 16 + (i & 15)) * 4 + (ja & 1) * 2] = aa;
    }
    if ((rlb & 3) != 3) {
      int i = g * 12 + (rlb >> 2) * 3 + (rlb & 3);
      uint2 aa = {packbf(fb.x, fb.y), packbf(fb.z, fb.w)};
      *(uint2*)&Asw[((size_t)(i >> 4) * 256 + (ja >> 1) * 16 + (i & 15)) * 4 + (ja & 1) * 2] = aa;
    }
  }
  __syncthreads();
  ((uint4*)Ksw)[(size_t)g * 256 + t] = ((const uint4*)tb)[t];  // coalesced 4 KB
}

// ---------------- K2: MFMA sim-GEMM + fused exp + diag + spike/mem ----------------
// R6-proven structure: 128 anchors x 1024 keys; af in regs; double-buffered
// 32 KB K tiles, prefetch-before-compute, 1 barrier/tile; launch_bounds(256,2).
constexpr int KSPLIT = 16;
constexpr int KEYS_PB = M / KSPLIT;   // 1024
constexpr int NT = KEYS_PB / 128;     // 8
constexpr int NBLK = KSPLIT * (NANCH / 128);  // 1536

__global__ __launch_bounds__(256, 2) void k_sim(
    const uint4* __restrict__ Ksw, const uint4* __restrict__ Asw,
    const float* __restrict__ MiL, const float* __restrict__ spikes,
    const float* __restrict__ mem, float* __restrict__ sumexp,
    float* __restrict__ simii, float* __restrict__ Pspike, float* __restrict__ Pmem) {
  __shared__ uint4 Tile[4096];  // buf0 = [0,2048), buf1 = [2048,4096)
  __shared__ float sbuf[2][4];
  const int tid = threadIdx.x;
  const int lane = tid & 63, w = tid >> 6;
  const int wm = w & 1, wn = w >> 1;
  const int wmo = wm * 64;
  const int a0 = blockIdx.y * 128;
  const int k0 = blockIdx.x * KEYS_PB;
  const int lcol = lane & 15, lhi = lane >> 4;
  const bool dblk = ((int)blockIdx.x == (int)(blockIdx.y >> 3));
  const int diagT2 = (a0 - k0) >> 7;  // valid only when dblk

  // stage A -> buf0 and K tile 0 -> buf1 (async)
  {
    const uint4* srcA = Asw + (size_t)a0 * 16;
    const uint4* srcK = Ksw + (size_t)k0 * 16;
#pragma unroll
    for (int it = 0; it < 8; ++it) {
      load_lds16(Tile + it * 256 + tid, srcA + it * 256 + tid);
      load_lds16(Tile + 2048 + it * 256 + tid, srcK + it * 256 + tid);
    }
  }
  __syncthreads();
  bf16x8 af[4][4];
#pragma unroll
  for (int mi = 0; mi < 4; ++mi)
#pragma unroll
    for (int ks = 0; ks < 4; ++ks)
      af[mi][ks] = *(const bf16x8*)(Tile + (wm * 4 + mi) * 256 + ks * 64 + lane);
  float nmiL[4][4];
#pragma unroll
  for (int mi = 0; mi < 4; ++mi)
#pragma unroll
    for (int r = 0; r < 4; ++r)
      nmiL[mi][r] = -MiL[a0 + wmo + mi * 16 + lhi * 4 + r];
  __syncthreads();  // all af reads complete before buf0 is reused for K

  float rs[4][4] = {};
  for (int t2 = 0; t2 < NT; ++t2) {
    uint4* cur = Tile + ((t2 & 1) ? 0 : 2048);
    uint4* nxt = Tile + ((t2 & 1) ? 2048 : 0);
    if (t2 + 1 < NT) {  // prefetch next tile while computing this one
      const uint4* src = Ksw + ((size_t)k0 + (t2 + 1) * 128) * 16;
#pragma unroll
      for (int it = 0; it < 8; ++it)
        load_lds16(nxt + it * 256 + tid, src + it * 256 + tid);
    }
    f32x4 acc[4][4] = {};
#pragma unroll
    for (int ks = 0; ks < 4; ++ks) {
      bf16x8 bfr[4];
#pragma unroll
      for (int nj = 0; nj < 4; ++nj)
        bfr[nj] = *(const bf16x8*)(cur + (wn * 4 + nj) * 256 + ks * 64 + lane);
#pragma unroll
      for (int mi = 0; mi < 4; ++mi)
#pragma unroll
        for (int nj = 0; nj < 4; ++nj)
          acc[mi][nj] = __builtin_amdgcn_mfma_f32_16x16x32_bf16(af[mi][ks], bfr[nj], acc[mi][nj], 0, 0, 0);
    }
    // diagonal extraction (verified R8): key col == anchor index here
    if (dblk && t2 == diagT2 && wm == wn && (lcol >> 2) == lhi) {
      int rr = lcol & 3;
#pragma unroll
      for (int mi = 0; mi < 4; ++mi) {
        f32x4 q = acc[mi][mi];
        float v = rr == 0 ? q[0] : rr == 1 ? q[1] : rr == 2 ? q[2] : q[3];
        simii[a0 + wmo + mi * 16 + lcol] = v;
      }
    }
    // fused epilogue: rs += 2^(sim*log2e - Mi*log2e)
#pragma unroll
    for (int mi = 0; mi < 4; ++mi)
#pragma unroll
      for (int nj = 0; nj < 4; ++nj)
#pragma unroll
        for (int r = 0; r < 4; ++r)
          rs[mi][r] += fast_exp2(fmaf(acc[mi][nj][r], 1.44269504088896f, nmiL[mi][r]));
    __syncthreads();  // cur reads done + nxt staged
  }

  // reduce over 16 key-columns, one atomic per anchor per wave
#pragma unroll
  for (int mi = 0; mi < 4; ++mi)
#pragma unroll
    for (int r = 0; r < 4; ++r) {
      float v = rs[mi][r];
      v += __shfl_xor(v, 1, 64);
      v += __shfl_xor(v, 2, 64);
      v += __shfl_xor(v, 4, 64);
      v += __shfl_xor(v, 8, 64);
      if (lcol == 0) atomicAdd(&sumexp[a0 + wmo + mi * 16 + lhi * 4 + r], v);
    }

  // fused spikes-mean + mem^2 partials (grid-stride over 524288 float4 each)
  {
    const int bid = blockIdx.y * KSPLIT + blockIdx.x;  // 0..1535
    const float4* s4 = (const float4*)spikes;
    const float4* m4 = (const float4*)mem;
    float ssp = 0.f, smm = 0.f;
    for (int i = bid * 256 + tid; i < ELEM / 4; i += NBLK * 256) {
      float4 a = s4[i];
      ssp += a.x + a.y + a.z + a.w;
    }
    for (int i = bid * 256 + tid; i < ELEM / 4; i += NBLK * 256) {
      float4 c = m4[i];
      smm += c.x * c.x + c.y * c.y + c.z * c.z + c.w * c.w;
    }
    ssp = waveRedSum(ssp);
    smm = waveRedSum(smm);
    if (lane == 0) { sbuf[0][w] = ssp; sbuf[1][w] = smm; }
    __syncthreads();
    if (tid == 0) {
      Pspike[bid] = sbuf[0][0] + sbuf[0][1] + sbuf[0][2] + sbuf[0][3];
      Pmem[bid]   = sbuf[1][0] + sbuf[1][1] + sbuf[1][2] + sbuf[1][3];
    }
  }
}

// ---------------- K3: elementwise ce + partials + last-block finalize ----------------
__global__ __launch_bounds__(256) void k_fin(
    const float* __restrict__ sumexp, const float* __restrict__ simii,
    const float* __restrict__ MiL, const int* __restrict__ targets,
    float* __restrict__ Pce, float* __restrict__ Pnv,
    const float* __restrict__ Pspike, const float* __restrict__ Pmem,
    uint* __restrict__ cnt, float* __restrict__ out) {
  int t = threadIdx.x, w = t >> 6, lane = t & 63;
  int i = blockIdx.x * 256 + t;
  float ce = 0.f, nv = 0.f;
  if (targets[i / 3] != 0) {
    // ce = Mi + ln(sumexp) - sim_ii ; Mi = MiL*ln2
    ce = 0.69314718055994531f * MiL[i] + __logf(sumexp[i]) - simii[i];
    nv = 1.f;
  }
  ce = waveRedSum(ce);
  nv = waveRedSum(nv);
  __shared__ float buf[2][4];
  __shared__ int isLast;
  if (lane == 0) { buf[0][w] = ce; buf[1][w] = nv; }
  __syncthreads();
  if (t == 0) {
    float pce = buf[0][0] + buf[0][1] + buf[0][2] + buf[0][3];
    float pnv = buf[1][0] + buf[1][1] + buf[1][2] + buf[1][3];
    __hip_atomic_store(&Pce[blockIdx.x], pce, __ATOMIC_RELAXED, __HIP_MEMORY_SCOPE_AGENT);
    __hip_atomic_store(&Pnv[blockIdx.x], pnv, __ATOMIC_RELAXED, __HIP_MEMORY_SCOPE_AGENT);
    __threadfence();
    uint prev = __hip_atomic_fetch_add(cnt, 1u, __ATOMIC_ACQ_REL, __HIP_MEMORY_SCOPE_AGENT);
    isLast = (prev == gridDim.x - 1);
  }
  __syncthreads();
  if (!isLast) return;

  float a = 0.f, b = 0.f, c = 0.f, e = 0.f;
#pragma unroll
  for (int j = 0; j < 6; ++j) {  // 1536 partials
    a += __hip_atomic_load(&Pspike[t + j * 256], __ATOMIC_RELAXED, __HIP_MEMORY_SCOPE_AGENT);
    b += __hip_atomic_load(&Pmem[t + j * 256], __ATOMIC_RELAXED, __HIP_MEMORY_SCOPE_AGENT);
  }
  if (t < 48) {
    c = __hip_atomic_load(&Pce[t], __ATOMIC_RELAXED, __HIP_MEMORY_SCOPE_AGENT);
    e = __hip_atomic_load(&Pnv[t], __ATOMIC_RELAXED, __HIP_MEMORY_SCOPE_AGENT);
  }
  a = waveRedSum(a); b = waveRedSum(b); c = waveRedSum(c); e = waveRedSum(e);
  __shared__ float fb2[4][4];
  if (lane == 0) { fb2[0][w] = a; fb2[1][w] = b; fb2[2][w] = c; fb2[3][w] = e; }
  __syncthreads();
  if (t == 0) {
    float ssp = fb2[0][0] + fb2[0][1] + fb2[0][2] + fb2[0][3];
    float smm = fb2[1][0] + fb2[1][1] + fb2[1][2] + fb2[1][3];
    float cet = fb2[2][0] + fb2[2][1] + fb2[2][2] + fb2[2][3];
    float nvt = fb2[3][0] + fb2[3][1] + fb2[3][2] + fb2[3][3];
    float spike_rate = ssp / (float)ELEM;
    float dr = spike_rate - 0.02f;
    float spike_reg = dr * dr;
    float mem_reg = smm / (float)ELEM;
    float tcl = cet / fmaxf(nvt, 1.0f);
    out[0] = tcl + 0.01f * spike_reg + 0.001f * mem_reg;
    out[1] = tcl;
    out[2] = spike_reg;
    out[3] = mem_reg;
    out[4] = spike_rate;
  }
}

extern "C" void kernel_launch(void* const* d_in, const int* in_sizes, int n_in,
                              void* d_out, int out_size, void* d_ws, size_t ws_size,
                              hipStream_t stream) {
  const float* H = (const float*)d_in[0];
  const int* targets = (const int*)d_in[1];
  const float* spikes = (const float*)d_in[2];
  const float* mem = (const float*)d_in[3];
  float* out = (float*)d_out;
  float* ws = (float*)d_ws;

  float* sumexp = ws;                      // [0, 12288)
  uint*  cnt    = (uint*)(ws + 12288);     // [12288]
  float* simii  = ws + 12292;              // +12288 -> 24580
  float* MiL    = ws + 24580;              // +12288 -> 36868
  float* Pspike = ws + 36868;              // +1536  -> 38404
  float* Pmem   = ws + 38404;              // +1536  -> 39940
  float* Pce    = ws + 39940;              // +48    -> 39988
  float* Pnv    = ws + 39988;              // +48    -> 40036
  uint*  Ksw    = (uint*)(ws + 40036);     // M*64 uints (16B aligned)
  uint*  Asw    = Ksw + (size_t)M * 64;    // NANCH*64 uints

  hipMemsetAsync(ws, 0, 12292 * sizeof(float), stream);  // sumexp + cnt
  k_prep<<<1024, 256, 0, stream>>>(H, Ksw, Asw, MiL);
  dim3 g2(KSPLIT, NANCH / 128);
  k_sim<<<g2, 256, 0, stream>>>((const uint4*)Ksw, (const uint4*)Asw, MiL,
                                spikes, mem, sumexp, simii, Pspike, Pmem);
  k_fin<<<NANCH / 256, 256, 0, stream>>>(sumexp, simii, MiL, targets, Pce, Pnv,
                                         Pspike, Pmem, cnt, out);
}